// Round 2
// baseline (343.939 us; speedup 1.0000x reference)
//
#include <hip/hip_runtime.h>
#include <math.h>

#define NN 256
#define LL 256
#define BB 16384
#define RPW 8          // rows per wave
#define WPB 4          // waves per block
#define RPB (RPW*WPB)  // rows per block = 32

// ---------------------------------------------------------------------------
// Coefficient precompute (double precision internally): diag/off per
// (layer, element), stored as float4 {d_re, d_im, o_re, o_im} at
// coef[l*256 + n].  1 MB total, L2-resident.
//
// ipsl[n]  = exp(i * (+/-) theta[l, n>>1] / 2)   (+ for even n, - for odd)
// epsl[n]  = exp(i * phi[l, n>>1]) for even n, 1 for odd n
// diag[n]  = 0.25 *   epsl[n]   * (2*ipsl[n] - ipsl[n+1] - ipsl[n-1])
// off[n]   = 0.25i *  epsl[n-1] * (2*ipsl[n] + ipsl[n+1] + ipsl[n-1])
// (indices mod 256)
// ---------------------------------------------------------------------------
__global__ void coef_kernel(const float* __restrict__ theta,
                            const float* __restrict__ phi,
                            float4* __restrict__ coef) {
    int idx = blockIdx.x * blockDim.x + threadIdx.x;
    if (idx >= LL * NN) return;
    int l = idx >> 8, n = idx & 255;
    int np = (n + 1) & 255, nm = (n - 1) & 255;
    const float* th = theta + l * (NN / 2);
    const float* ph = phi + l * (NN / 2);
    double s, c, a;
    a = (double)th[n >> 1]  * ((n  & 1) ? -0.5 : 0.5);
    sincos(a, &s, &c); double inr = c, ini = s;
    a = (double)th[np >> 1] * ((np & 1) ? -0.5 : 0.5);
    sincos(a, &s, &c); double ipr = c, ipi = s;
    a = (double)th[nm >> 1] * ((nm & 1) ? -0.5 : 0.5);
    sincos(a, &s, &c); double imr = c, imi = s;
    double enr = 1.0, eni = 0.0, emr = 1.0, emi = 0.0;
    if (!(n & 1))  { sincos((double)ph[n >> 1],  &s, &c); enr = c; eni = s; }
    if (!(nm & 1)) { sincos((double)ph[nm >> 1], &s, &c); emr = c; emi = s; }
    // diag = 0.25 * en * (2*in - ip - im)
    double dr = 2.0 * inr - ipr - imr;
    double di = 2.0 * ini - ipi - imi;
    double diag_re = 0.25 * (enr * dr - eni * di);
    double diag_im = 0.25 * (enr * di + eni * dr);
    // off = 0.25i * em * (2*in + ip + im)
    double orv = 2.0 * inr + ipr + imr;
    double oiv = 2.0 * ini + ipi + imi;
    double tre = emr * orv - emi * oiv;
    double tim = emr * oiv + emi * orv;
    coef[idx] = make_float4((float)diag_re, (float)diag_im,
                            (float)(-0.25 * tim), (float)(0.25 * tre));
}

// ---------------------------------------------------------------------------
// One layer: circular shift by S (0, +1, -1), then pairwise 2x2 coupling:
//   y[2k]   = t[2k]*d[2k]   + t[2k+1]*o[2k+1]
//   y[2k+1] = t[2k+1]*d[2k+1] + t[2k]*o[2k]
// Lane holds elements 4*lane..4*lane+3 -> pairs are intra-lane; only the
// boundary element of a shift crosses lanes (2 shuffles per row).
// ---------------------------------------------------------------------------
template<int S>
__device__ __forceinline__ void apply_layer(float (&xr)[RPW][4], float (&xi)[RPW][4],
                                            const float4 (&c)[4], int lane) {
#pragma unroll
    for (int r = 0; r < RPW; ++r) {
        float t0r, t0i, t1r, t1i, t2r, t2i, t3r, t3i;
        if (S == 0) {
            t0r = xr[r][0]; t0i = xi[r][0];
            t1r = xr[r][1]; t1i = xi[r][1];
            t2r = xr[r][2]; t2i = xi[r][2];
            t3r = xr[r][3]; t3i = xi[r][3];
        } else if (S == 1) {           // xs[i] = x[i+1]
            t0r = xr[r][1]; t0i = xi[r][1];
            t1r = xr[r][2]; t1i = xi[r][2];
            t2r = xr[r][3]; t2i = xi[r][3];
            t3r = __shfl(xr[r][0], (lane + 1) & 63, 64);
            t3i = __shfl(xi[r][0], (lane + 1) & 63, 64);
        } else {                       // S == -1: xs[i] = x[i-1]
            t0r = __shfl(xr[r][3], (lane + 63) & 63, 64);
            t0i = __shfl(xi[r][3], (lane + 63) & 63, 64);
            t1r = xr[r][0]; t1i = xi[r][0];
            t2r = xr[r][1]; t2i = xi[r][1];
            t3r = xr[r][2]; t3i = xi[r][2];
        }
        xr[r][0] = t0r*c[0].x - t0i*c[0].y + t1r*c[1].z - t1i*c[1].w;
        xi[r][0] = t0r*c[0].y + t0i*c[0].x + t1r*c[1].w + t1i*c[1].z;
        xr[r][1] = t1r*c[1].x - t1i*c[1].y + t0r*c[0].z - t0i*c[0].w;
        xi[r][1] = t1r*c[1].y + t1i*c[1].x + t0r*c[0].w + t0i*c[0].z;
        xr[r][2] = t2r*c[2].x - t2i*c[2].y + t3r*c[3].z - t3i*c[3].w;
        xi[r][2] = t2r*c[2].y + t2i*c[2].x + t3r*c[3].w + t3i*c[3].z;
        xr[r][3] = t3r*c[3].x - t3i*c[3].y + t2r*c[2].z - t2i*c[2].w;
        xi[r][3] = t3r*c[3].y + t3i*c[3].x + t2r*c[2].w + t2i*c[2].z;
    }
}

__global__ __launch_bounds__(WPB * 64, 2) void mesh_kernel(
        const float* __restrict__ x_re, const float* __restrict__ x_im,
        const float* __restrict__ gamma, const float4* __restrict__ coef,
        float* __restrict__ out) {
    const int lane = threadIdx.x & 63;
    const int wave = threadIdx.x >> 6;
    const int row0 = (blockIdx.x * WPB + wave) * RPW;

    float xr[RPW][4], xi[RPW][4];

    // Input phase screen exp(i*gamma), double-precision sincos
    float4 g = ((const float4*)gamma)[lane];
    float ga[4] = {g.x, g.y, g.z, g.w};
    float gc[4], gs[4];
#pragma unroll
    for (int j = 0; j < 4; ++j) {
        double ds, dc;
        sincos((double)ga[j], &ds, &dc);
        gs[j] = (float)ds; gc[j] = (float)dc;
    }

    const float4* xre4 = (const float4*)x_re;
    const float4* xim4 = (const float4*)x_im;
#pragma unroll
    for (int r = 0; r < RPW; ++r) {
        float4 vr = xre4[(row0 + r) * 64 + lane];
        float4 vi = xim4[(row0 + r) * 64 + lane];
        float ar[4] = {vr.x, vr.y, vr.z, vr.w};
        float ai[4] = {vi.x, vi.y, vi.z, vi.w};
#pragma unroll
        for (int j = 0; j < 4; ++j) {
            xr[r][j] = ar[j] * gc[j] - ai[j] * gs[j];
            xi[r][j] = ar[j] * gs[j] + ai[j] * gc[j];
        }
    }

    float4 c[4];
    const float4* cp = coef + 4 * lane;   // this lane's 4 elements within a layer

    // layer 0: shift 0
#pragma unroll
    for (int j = 0; j < 4; ++j) c[j] = cp[j];
    apply_layer<0>(xr, xi, c, lane);

    // layers 1..254 in (+1, -1) pairs
#pragma unroll 1
    for (int l = 1; l < LL - 1; l += 2) {
#pragma unroll
        for (int j = 0; j < 4; ++j) c[j] = cp[l * 256 + j];
        apply_layer<1>(xr, xi, c, lane);
#pragma unroll
        for (int j = 0; j < 4; ++j) c[j] = cp[(l + 1) * 256 + j];
        apply_layer<-1>(xr, xi, c, lane);
    }

    // layer 255: shift +1
#pragma unroll
    for (int j = 0; j < 4; ++j) c[j] = cp[(LL - 1) * 256 + j];
    apply_layer<1>(xr, xi, c, lane);

    // final permutation: y[i] = x[i-1]  (shift right by 1), then store
    float* out_re = out;
    float* out_im = out + (size_t)BB * NN;
#pragma unroll
    for (int r = 0; r < RPW; ++r) {
        float f0r = __shfl(xr[r][3], (lane + 63) & 63, 64);
        float f0i = __shfl(xi[r][3], (lane + 63) & 63, 64);
        float4 vr = make_float4(f0r, xr[r][0], xr[r][1], xr[r][2]);
        float4 vi = make_float4(f0i, xi[r][0], xi[r][1], xi[r][2]);
        ((float4*)out_re)[(row0 + r) * 64 + lane] = vr;
        ((float4*)out_im)[(row0 + r) * 64 + lane] = vi;
    }
}

extern "C" void kernel_launch(void* const* d_in, const int* in_sizes, int n_in,
                              void* d_out, int out_size, void* d_ws, size_t ws_size,
                              hipStream_t stream) {
    const float* x_re  = (const float*)d_in[0];
    const float* x_im  = (const float*)d_in[1];
    const float* theta = (const float*)d_in[2];
    const float* phi   = (const float*)d_in[3];
    const float* gamma = (const float*)d_in[4];
    // d_in[5] = perm_idx, d_in[6] = pairwise_perm_idx: deterministic
    // rectangular-mesh structure (shift 0,+1,-1,... ; pair swap) is hardcoded.

    float4* coef = (float4*)d_ws;   // LL*NN float4 = 1 MB

    hipLaunchKernelGGL(coef_kernel, dim3((LL * NN) / 256), dim3(256), 0, stream,
                       theta, phi, coef);
    hipLaunchKernelGGL(mesh_kernel, dim3(BB / RPB), dim3(WPB * 64), 0, stream,
                       x_re, x_im, gamma, coef, (float*)d_out);
}

// Round 3
// 337.228 us; speedup vs baseline: 1.0199x; 1.0199x over previous
//
#include <hip/hip_runtime.h>
#include <math.h>

#define NN 256
#define LL 256
#define BB 16384
#define RPW 8          // rows per wave
#define WPB 4          // waves per block
#define RPB (RPW*WPB)  // rows per block = 32

// ===========================================================================
// Shift-free ("y-frame") formulation.
// Reference per layer l: x' [i] = d_l[i] * x_s[i] + o_l[i^1] * x_s[i^1],
// where x_s = x shifted by s_l (s = 0,+1,-1,+1,...,+1), plus a final shift.
// Tracking cumulative shift u (alternates 0,1), in the unshifted frame:
//   y'[j] = D[j]*y[j] + O[j]*y[partner(j)]
//   u = l&1;  D[j] = d_l[(j-u)&255];  O[j] = o_l[((j-u)&255)^1]
//   partner: u=0 -> j^1 (even pairs), u=1 -> odd pairs (2k+1,2k+2)
// The final permutation exactly cancels u_final=1, so output = y. The input
// phase screen exp(i*gamma) folds into layer-0 coefficients (f64 precompute).
// Coefs stored plane-arranged: A[l*256 + (j&3)*64 + (j>>2)] = {Dre,Dim,Ore,Oim}
// so lane L's element (4L+j) coef sits at plane j, slot L -> conflict-free
// ds_read_b128 and linear global_load_lds staging.
// ===========================================================================
__global__ void coef_kernel(const float* __restrict__ theta,
                            const float* __restrict__ phi,
                            const float* __restrict__ gamma,
                            float4* __restrict__ coef) {
    int idx = blockIdx.x * blockDim.x + threadIdx.x;
    if (idx >= LL * NN) return;
    int l = idx >> 8, j = idx & 255;
    int u = l & 1;
    int n = (j - u) & 255;      // diag source element
    int m = n ^ 1;              // off source element
    const float* th = theta + l * (NN / 2);
    const float* ph = phi + l * (NN / 2);

    // ipsl[k] = exp(i * (+/-)theta[k>>1]/2); epsl[k] = exp(i*phi[k>>1]) if k even else 1
    auto ipsl = [&](int k, double& re, double& im) {
        k &= 255;
        double a = (double)th[k >> 1] * ((k & 1) ? -0.5 : 0.5);
        double s, c; sincos(a, &s, &c); re = c; im = s;
    };
    double s, c;
    // D = 0.25 * epsl[n] * (2*ipsl[n] - ipsl[n+1] - ipsl[n-1])
    double inr, ini, ipr, ipi, imr, imi;
    ipsl(n, inr, ini); ipsl(n + 1, ipr, ipi); ipsl(n - 1, imr, imi);
    double enr = 1.0, eni = 0.0;
    if (!(n & 1)) { sincos((double)ph[n >> 1], &s, &c); enr = c; eni = s; }
    double dr = 2.0 * inr - ipr - imr;
    double di = 2.0 * ini - ipi - imi;
    double Dre = 0.25 * (enr * dr - eni * di);
    double Dim = 0.25 * (enr * di + eni * dr);
    // O = 0.25i * epsl[m-1] * (2*ipsl[m] + ipsl[m+1] + ipsl[m-1])
    ipsl(m, inr, ini); ipsl(m + 1, ipr, ipi); ipsl(m - 1, imr, imi);
    int mm = (m - 1) & 255;
    double emr = 1.0, emi = 0.0;
    if (!(mm & 1)) { sincos((double)ph[mm >> 1], &s, &c); emr = c; emi = s; }
    double orv = 2.0 * inr + ipr + imr;
    double oiv = 2.0 * ini + ipi + imi;
    double tre = emr * orv - emi * oiv;
    double tim = emr * oiv + emi * orv;
    double Ore = -0.25 * tim;
    double Oim =  0.25 * tre;

    if (l == 0) {
        // fold input phase screen: D *= e^{i*g[j]}, O *= e^{i*g[j^1]} (u=0 -> partner j^1)
        double gs, gc;
        sincos((double)gamma[j], &gs, &gc);
        double a2 = Dre * gc - Dim * gs, b2 = Dre * gs + Dim * gc;
        Dre = a2; Dim = b2;
        sincos((double)gamma[j ^ 1], &gs, &gc);
        a2 = Ore * gc - Oim * gs; b2 = Ore * gs + Oim * gc;
        Ore = a2; Oim = b2;
    }
    coef[l * 256 + (j & 3) * 64 + (j >> 2)] =
        make_float4((float)Dre, (float)Dim, (float)Ore, (float)Oim);
}

// ---------------------------------------------------------------------------
// Packed complex MZI update: out = D*y + O*p (complex), 4 VOP3P ops.
//   I1: t  = (-Oi*pi           ,  Oi*pr          )
//   I2: t += ( Or*pr           ,  Or*pi          )   -> O*p
//   I3: t += (-Di*yi           ,  Di*yr          )
//   I4: t += ( Dr*yr           ,  Dr*yi          )   -> D*y + O*p
// cD=(Dr,Di), cO=(Or,Oi); op_sel does splat/swap, neg_lo the sign.
// ---------------------------------------------------------------------------
__device__ __forceinline__ float2 mzi(float2 cD, float2 cO, float2 y, float2 p) {
    float2 t;
    asm("v_pk_mul_f32 %0, %1, %2 op_sel:[1,1] op_sel_hi:[1,0] neg_lo:[1,0]"
        : "=v"(t) : "v"(cO), "v"(p));
    asm("v_pk_fma_f32 %0, %1, %2, %0 op_sel:[0,0,0] op_sel_hi:[0,1,1]"
        : "+v"(t) : "v"(cO), "v"(p));
    asm("v_pk_fma_f32 %0, %1, %2, %0 op_sel:[1,1,0] op_sel_hi:[1,0,1] neg_lo:[1,0,0]"
        : "+v"(t) : "v"(cD), "v"(y));
    asm("v_pk_fma_f32 %0, %1, %2, %0 op_sel:[0,0,0] op_sel_hi:[0,1,1]"
        : "+v"(t) : "v"(cD), "v"(y));
    return t;
}

__global__ __launch_bounds__(WPB * 64, 2) void mesh_kernel(
        const float* __restrict__ x_re, const float* __restrict__ x_im,
        const float4* __restrict__ coef, float* __restrict__ out) {
    const int lane = threadIdx.x & 63;
    const int wave = threadIdx.x >> 6;
    const int row0 = (blockIdx.x * WPB + wave) * RPW;
    const int laneL = (lane + 63) & 63;
    const int laneR = (lane + 1) & 63;

    // double-buffered 2-layer coef staging: [buf][layer][plane*64+lane]
    __shared__ float4 smem[2][2][256];

    float2 y[RPW][4];

    const float4* xre4 = (const float4*)x_re;
    const float4* xim4 = (const float4*)x_im;
#pragma unroll
    for (int r = 0; r < RPW; ++r) {
        float4 vr = xre4[(row0 + r) * 64 + lane];
        float4 vi = xim4[(row0 + r) * 64 + lane];
        y[r][0] = make_float2(vr.x, vi.x);
        y[r][1] = make_float2(vr.y, vi.y);
        y[r][2] = make_float2(vr.z, vi.z);
        y[r][3] = make_float2(vr.w, vi.w);
    }

    // stage 8KB (2 layers) for iteration `it` into buffer b:
    // wave w handles 1KB chunks (w) and (4+w); linear on both sides.
    const char* cbase = (const char*)coef;
    auto stage = [&](int b, int it) {
#pragma unroll
        for (int q = 0; q < 2; ++q) {
            int chunk = q * 4 + wave;
            const char* src = cbase + (size_t)it * 8192 + chunk * 1024 + lane * 16;
            char* dst = (char*)&smem[b][0][0] + chunk * 1024 + lane * 16;
            __builtin_amdgcn_global_load_lds(
                (const __attribute__((address_space(1))) unsigned int*)src,
                (__attribute__((address_space(3))) unsigned int*)dst, 16, 0, 0);
        }
    };

    stage(0, 0);
    __syncthreads();

#pragma unroll 1
    for (int it = 0; it < 128; ++it) {
        const int b = it & 1;
        if (it < 127) stage(b ^ 1, it + 1);

        // ---- even layer (2*it): intra-lane pairs (0,1),(2,3), no shuffles
        {
            float4 c0 = smem[b][0][0 * 64 + lane];
            float4 c1 = smem[b][0][1 * 64 + lane];
            float4 c2 = smem[b][0][2 * 64 + lane];
            float4 c3 = smem[b][0][3 * 64 + lane];
#pragma unroll
            for (int r = 0; r < RPW; ++r) {
                float2 y0 = y[r][0], y1 = y[r][1], y2 = y[r][2], y3 = y[r][3];
                y[r][0] = mzi(make_float2(c0.x, c0.y), make_float2(c0.z, c0.w), y0, y1);
                y[r][1] = mzi(make_float2(c1.x, c1.y), make_float2(c1.z, c1.w), y1, y0);
                y[r][2] = mzi(make_float2(c2.x, c2.y), make_float2(c2.z, c2.w), y2, y3);
                y[r][3] = mzi(make_float2(c3.x, c3.y), make_float2(c3.z, c3.w), y3, y2);
            }
        }
        // ---- odd layer (2*it+1): pairs (4L-1,4L),(4L+1,4L+2),(4L+3,4L+4)
        {
            float4 c0 = smem[b][1][0 * 64 + lane];
            float4 c1 = smem[b][1][1 * 64 + lane];
            float4 c2 = smem[b][1][2 * 64 + lane];
            float4 c3 = smem[b][1][3 * 64 + lane];
#pragma unroll
            for (int r = 0; r < RPW; ++r) {
                float2 y0 = y[r][0], y1 = y[r][1], y2 = y[r][2], y3 = y[r][3];
                float2 p0 = make_float2(__shfl(y3.x, laneL, 64), __shfl(y3.y, laneL, 64));
                float2 p3 = make_float2(__shfl(y0.x, laneR, 64), __shfl(y0.y, laneR, 64));
                y[r][0] = mzi(make_float2(c0.x, c0.y), make_float2(c0.z, c0.w), y0, p0);
                y[r][1] = mzi(make_float2(c1.x, c1.y), make_float2(c1.z, c1.w), y1, y2);
                y[r][2] = mzi(make_float2(c2.x, c2.y), make_float2(c2.z, c2.w), y2, y1);
                y[r][3] = mzi(make_float2(c3.x, c3.y), make_float2(c3.z, c3.w), y3, p3);
            }
        }
        __syncthreads();
    }

    // output = y directly (final permutation cancelled by the frame)
    float* out_re = out;
    float* out_im = out + (size_t)BB * NN;
#pragma unroll
    for (int r = 0; r < RPW; ++r) {
        float4 vr = make_float4(y[r][0].x, y[r][1].x, y[r][2].x, y[r][3].x);
        float4 vi = make_float4(y[r][0].y, y[r][1].y, y[r][2].y, y[r][3].y);
        ((float4*)out_re)[(row0 + r) * 64 + lane] = vr;
        ((float4*)out_im)[(row0 + r) * 64 + lane] = vi;
    }
}

extern "C" void kernel_launch(void* const* d_in, const int* in_sizes, int n_in,
                              void* d_out, int out_size, void* d_ws, size_t ws_size,
                              hipStream_t stream) {
    const float* x_re  = (const float*)d_in[0];
    const float* x_im  = (const float*)d_in[1];
    const float* theta = (const float*)d_in[2];
    const float* phi   = (const float*)d_in[3];
    const float* gamma = (const float*)d_in[4];
    // d_in[5]/d_in[6]: deterministic mesh permutations, folded analytically.

    float4* coef = (float4*)d_ws;   // LL*NN float4 = 1 MB, plane-arranged

    hipLaunchKernelGGL(coef_kernel, dim3((LL * NN) / 256), dim3(256), 0, stream,
                       theta, phi, gamma, coef);
    hipLaunchKernelGGL(mesh_kernel, dim3(BB / RPB), dim3(WPB * 64), 0, stream,
                       x_re, x_im, coef, (float*)d_out);
}

// Round 4
// 308.455 us; speedup vs baseline: 1.1150x; 1.0933x over previous
//
#include <hip/hip_runtime.h>
#include <math.h>

#define NN 256
#define LL 256
#define BB 16384
#define WPB 4            // waves per block
#define ROWS_PER_WAVE 8  // 4 slots x 2 rows (lane halves)

// ===========================================================================
// Shift-free ("y-frame") formulation (validated round 3):
//   u = l&1;  D[j] = d_l[(j-u)&255];  O[j] = o_l[((j-u)&255)^1]
//   partner: u=0 -> j^1; u=1 -> (2k+1,2k+2) pairs (j even -> j-1, j odd -> j+1)
// Final permutation cancels; gamma folded into layer-0 coefs (f64).
// Layout for this round: lane half h=lane>>5 is one row; l32=lane&31 owns
// elements 8*l32 .. 8*l32+7.  Coef store: coef[l*256 + (j&7)*32 + (j>>3)]
// so lane l32 reads plane jj at byte offset jj*512 + l32*16 (coalesced,
// lane halves duplicate -> L2-friendly).
// ===========================================================================
__global__ void coef_kernel(const float* __restrict__ theta,
                            const float* __restrict__ phi,
                            const float* __restrict__ gamma,
                            float4* __restrict__ coef) {
    int idx = blockIdx.x * blockDim.x + threadIdx.x;
    if (idx >= LL * NN) return;
    int l = idx >> 8, j = idx & 255;
    int u = l & 1;
    int n = (j - u) & 255;      // diag source element
    int m = n ^ 1;              // off source element
    const float* th = theta + l * (NN / 2);
    const float* ph = phi + l * (NN / 2);

    auto ipsl = [&](int k, double& re, double& im) {
        k &= 255;
        double a = (double)th[k >> 1] * ((k & 1) ? -0.5 : 0.5);
        double s, c; sincos(a, &s, &c); re = c; im = s;
    };
    double s, c;
    double inr, ini, ipr, ipi, imr, imi;
    ipsl(n, inr, ini); ipsl(n + 1, ipr, ipi); ipsl(n - 1, imr, imi);
    double enr = 1.0, eni = 0.0;
    if (!(n & 1)) { sincos((double)ph[n >> 1], &s, &c); enr = c; eni = s; }
    double dr = 2.0 * inr - ipr - imr;
    double di = 2.0 * ini - ipi - imi;
    double Dre = 0.25 * (enr * dr - eni * di);
    double Dim = 0.25 * (enr * di + eni * dr);
    ipsl(m, inr, ini); ipsl(m + 1, ipr, ipi); ipsl(m - 1, imr, imi);
    int mm = (m - 1) & 255;
    double emr = 1.0, emi = 0.0;
    if (!(mm & 1)) { sincos((double)ph[mm >> 1], &s, &c); emr = c; emi = s; }
    double orv = 2.0 * inr + ipr + imr;
    double oiv = 2.0 * ini + ipi + imi;
    double tre = emr * orv - emi * oiv;
    double tim = emr * oiv + emi * orv;
    double Ore = -0.25 * tim;
    double Oim =  0.25 * tre;

    if (l == 0) {
        double gs, gc;
        sincos((double)gamma[j], &gs, &gc);
        double a2 = Dre * gc - Dim * gs, b2 = Dre * gs + Dim * gc;
        Dre = a2; Dim = b2;
        sincos((double)gamma[j ^ 1], &gs, &gc);
        a2 = Ore * gc - Oim * gs; b2 = Ore * gs + Oim * gc;
        Ore = a2; Oim = b2;
    }
    coef[l * 256 + (j & 7) * 32 + (j >> 3)] =
        make_float4((float)Dre, (float)Dim, (float)Ore, (float)Oim);
}

// Packed complex MZI update: out = D*y + O*p (validated round 3).
__device__ __forceinline__ float2 mzi(float2 cD, float2 cO, float2 y, float2 p) {
    float2 t;
    asm("v_pk_mul_f32 %0, %1, %2 op_sel:[1,1] op_sel_hi:[1,0] neg_lo:[1,0]"
        : "=v"(t) : "v"(cO), "v"(p));
    asm("v_pk_fma_f32 %0, %1, %2, %0 op_sel:[0,0,0] op_sel_hi:[0,1,1]"
        : "+v"(t) : "v"(cO), "v"(p));
    asm("v_pk_fma_f32 %0, %1, %2, %0 op_sel:[1,1,0] op_sel_hi:[1,0,1] neg_lo:[1,0,0]"
        : "+v"(t) : "v"(cD), "v"(y));
    asm("v_pk_fma_f32 %0, %1, %2, %0 op_sel:[0,0,0] op_sel_hi:[0,1,1]"
        : "+v"(t) : "v"(cD), "v"(y));
    return t;
}

__device__ __forceinline__ float2 D_(float4 c) { return make_float2(c.x, c.y); }
__device__ __forceinline__ float2 O_(float4 c) { return make_float2(c.z, c.w); }

__global__ __launch_bounds__(WPB * 64, 2) void mesh_kernel(
        const float* __restrict__ x_re, const float* __restrict__ x_im,
        const float4* __restrict__ coef, float* __restrict__ out) {
    const int lane = threadIdx.x & 63;
    const int wave = threadIdx.x >> 6;
    const int l32  = lane & 31;
    const int half = lane >> 5;
    const int row0 = (blockIdx.x * WPB + wave) * ROWS_PER_WAVE;
    // bpermute byte indices (stay within lane half)
    const int idxL4 = (((lane & 32) | ((lane - 1) & 31))) << 2;
    const int idxR4 = (((lane & 32) | ((lane + 1) & 31))) << 2;

    float2 y[4][8];   // [row-pair slot][element] — all indices static after unroll

    const float4* xre4 = (const float4*)x_re;
    const float4* xim4 = (const float4*)x_im;
#pragma unroll
    for (int s2 = 0; s2 < 4; ++s2) {
        int row = row0 + 2 * s2 + half;
        float4 vr0 = xre4[row * 64 + 2 * l32];
        float4 vr1 = xre4[row * 64 + 2 * l32 + 1];
        float4 vi0 = xim4[row * 64 + 2 * l32];
        float4 vi1 = xim4[row * 64 + 2 * l32 + 1];
        y[s2][0] = make_float2(vr0.x, vi0.x);
        y[s2][1] = make_float2(vr0.y, vi0.y);
        y[s2][2] = make_float2(vr0.z, vi0.z);
        y[s2][3] = make_float2(vr0.w, vi0.w);
        y[s2][4] = make_float2(vr1.x, vi1.x);
        y[s2][5] = make_float2(vr1.y, vi1.y);
        y[s2][6] = make_float2(vr1.z, vi1.z);
        y[s2][7] = make_float2(vr1.w, vi1.w);
    }

    const float4* cp = coef + l32;   // + l*256 + j*32 per layer/plane
    auto loadl = [&](int l, float4& c0, float4& c1, float4& c2, float4& c3,
                            float4& c4, float4& c5, float4& c6, float4& c7) {
        const float4* p = cp + l * 256;
        c0 = p[0 * 32]; c1 = p[1 * 32]; c2 = p[2 * 32]; c3 = p[3 * 32];
        c4 = p[4 * 32]; c5 = p[5 * 32]; c6 = p[6 * 32]; c7 = p[7 * 32];
    };

    float4 a0, a1, a2, a3, a4, a5, a6, a7;   // even-layer coefs
    float4 b0, b1, b2, b3, b4, b5, b6, b7;   // odd-layer coefs
    loadl(0, a0, a1, a2, a3, a4, a5, a6, a7);

#pragma unroll 1
    for (int it = 0; it < 128; ++it) {
        loadl(2 * it + 1, b0, b1, b2, b3, b4, b5, b6, b7);
        // ---- even layer: intra-lane pairs (0,1),(2,3),(4,5),(6,7)
#pragma unroll
        for (int s2 = 0; s2 < 4; ++s2) {
            float2 t0 = y[s2][0], t1 = y[s2][1], t2 = y[s2][2], t3 = y[s2][3];
            float2 t4 = y[s2][4], t5 = y[s2][5], t6 = y[s2][6], t7 = y[s2][7];
            y[s2][0] = mzi(D_(a0), O_(a0), t0, t1);
            y[s2][1] = mzi(D_(a1), O_(a1), t1, t0);
            y[s2][2] = mzi(D_(a2), O_(a2), t2, t3);
            y[s2][3] = mzi(D_(a3), O_(a3), t3, t2);
            y[s2][4] = mzi(D_(a4), O_(a4), t4, t5);
            y[s2][5] = mzi(D_(a5), O_(a5), t5, t4);
            y[s2][6] = mzi(D_(a6), O_(a6), t6, t7);
            y[s2][7] = mzi(D_(a7), O_(a7), t7, t6);
        }
        if (it < 127) loadl(2 * it + 2, a0, a1, a2, a3, a4, a5, a6, a7);
        // ---- odd layer: pairs (8L-1,8L),(1,2),(3,4),(5,6),(8L+7,8L+8)
#pragma unroll
        for (int s2 = 0; s2 < 4; ++s2) {
            float2 t0 = y[s2][0], t1 = y[s2][1], t2 = y[s2][2], t3 = y[s2][3];
            float2 t4 = y[s2][4], t5 = y[s2][5], t6 = y[s2][6], t7 = y[s2][7];
            float2 plo, phi2;
            plo.x  = __int_as_float(__builtin_amdgcn_ds_bpermute(idxL4, __float_as_int(t7.x)));
            plo.y  = __int_as_float(__builtin_amdgcn_ds_bpermute(idxL4, __float_as_int(t7.y)));
            phi2.x = __int_as_float(__builtin_amdgcn_ds_bpermute(idxR4, __float_as_int(t0.x)));
            phi2.y = __int_as_float(__builtin_amdgcn_ds_bpermute(idxR4, __float_as_int(t0.y)));
            y[s2][1] = mzi(D_(b1), O_(b1), t1, t2);
            y[s2][2] = mzi(D_(b2), O_(b2), t2, t1);
            y[s2][3] = mzi(D_(b3), O_(b3), t3, t4);
            y[s2][4] = mzi(D_(b4), O_(b4), t4, t3);
            y[s2][5] = mzi(D_(b5), O_(b5), t5, t6);
            y[s2][6] = mzi(D_(b6), O_(b6), t6, t5);
            y[s2][0] = mzi(D_(b0), O_(b0), t0, plo);
            y[s2][7] = mzi(D_(b7), O_(b7), t7, phi2);
        }
    }

    // output = y directly (final permutation cancelled by the frame)
    float* out_re = out;
    float* out_im = out + (size_t)BB * NN;
#pragma unroll
    for (int s2 = 0; s2 < 4; ++s2) {
        int row = row0 + 2 * s2 + half;
        float4 vr0 = make_float4(y[s2][0].x, y[s2][1].x, y[s2][2].x, y[s2][3].x);
        float4 vr1 = make_float4(y[s2][4].x, y[s2][5].x, y[s2][6].x, y[s2][7].x);
        float4 vi0 = make_float4(y[s2][0].y, y[s2][1].y, y[s2][2].y, y[s2][3].y);
        float4 vi1 = make_float4(y[s2][4].y, y[s2][5].y, y[s2][6].y, y[s2][7].y);
        ((float4*)out_re)[row * 64 + 2 * l32]     = vr0;
        ((float4*)out_re)[row * 64 + 2 * l32 + 1] = vr1;
        ((float4*)out_im)[row * 64 + 2 * l32]     = vi0;
        ((float4*)out_im)[row * 64 + 2 * l32 + 1] = vi1;
    }
}

extern "C" void kernel_launch(void* const* d_in, const int* in_sizes, int n_in,
                              void* d_out, int out_size, void* d_ws, size_t ws_size,
                              hipStream_t stream) {
    const float* x_re  = (const float*)d_in[0];
    const float* x_im  = (const float*)d_in[1];
    const float* theta = (const float*)d_in[2];
    const float* phi   = (const float*)d_in[3];
    const float* gamma = (const float*)d_in[4];

    float4* coef = (float4*)d_ws;   // LL*NN float4 = 1 MB, plane-arranged

    hipLaunchKernelGGL(coef_kernel, dim3((LL * NN) / 256), dim3(256), 0, stream,
                       theta, phi, gamma, coef);
    hipLaunchKernelGGL(mesh_kernel, dim3(BB / (WPB * ROWS_PER_WAVE)), dim3(WPB * 64),
                       0, stream, x_re, x_im, coef, (float*)d_out);
}

// Round 5
// 198.086 us; speedup vs baseline: 1.7363x; 1.5572x over previous
//
#include <hip/hip_runtime.h>
#include <math.h>

#define NN 256
#define LL 256
#define BB 16384

typedef __attribute__((ext_vector_type(8))) short short8;
typedef __attribute__((ext_vector_type(4))) float f32x4;

// ===========================================================================
// ws layout (bytes):
//   [0,       1 MB)   coef   (float4[65536], plane-arranged, validated r3/r4)
//   [1.0 MB, 1.5 MB)  PA     (float2[256*256])  = (T_127...T_0)^T
//   [1.5 MB, 2.0 MB)  PB     (float2[256*256])  = (T_255...T_128)^T
//   [2.0 MB, 2.5 MB)  Cm     (float2[256*256])  = PA*PB  (out = x * Cm)
//   [2.5 MB, 4.0 MB)  Wt     (ushort[3][512][512]) bf16x3 planes of W^T
// ===========================================================================

// --------------------------------------------------------------------------
// Coefficient precompute (validated rounds 3/4, unchanged).
// --------------------------------------------------------------------------
__global__ void coef_kernel(const float* __restrict__ theta,
                            const float* __restrict__ phi,
                            const float* __restrict__ gamma,
                            float4* __restrict__ coef) {
    int idx = blockIdx.x * blockDim.x + threadIdx.x;
    if (idx >= LL * NN) return;
    int l = idx >> 8, j = idx & 255;
    int u = l & 1;
    int n = (j - u) & 255;
    int m = n ^ 1;
    const float* th = theta + l * (NN / 2);
    const float* ph = phi + l * (NN / 2);

    auto ipsl = [&](int k, double& re, double& im) {
        k &= 255;
        double a = (double)th[k >> 1] * ((k & 1) ? -0.5 : 0.5);
        double s, c; sincos(a, &s, &c); re = c; im = s;
    };
    double s, c;
    double inr, ini, ipr, ipi, imr, imi;
    ipsl(n, inr, ini); ipsl(n + 1, ipr, ipi); ipsl(n - 1, imr, imi);
    double enr = 1.0, eni = 0.0;
    if (!(n & 1)) { sincos((double)ph[n >> 1], &s, &c); enr = c; eni = s; }
    double dr = 2.0 * inr - ipr - imr;
    double di = 2.0 * ini - ipi - imi;
    double Dre = 0.25 * (enr * dr - eni * di);
    double Dim = 0.25 * (enr * di + eni * dr);
    ipsl(m, inr, ini); ipsl(m + 1, ipr, ipi); ipsl(m - 1, imr, imi);
    int mm = (m - 1) & 255;
    double emr = 1.0, emi = 0.0;
    if (!(mm & 1)) { sincos((double)ph[mm >> 1], &s, &c); emr = c; emi = s; }
    double orv = 2.0 * inr + ipr + imr;
    double oiv = 2.0 * ini + ipi + imi;
    double tre = emr * orv - emi * oiv;
    double tim = emr * oiv + emi * orv;
    double Ore = -0.25 * tim;
    double Oim =  0.25 * tre;

    if (l == 0) {
        double gs, gc;
        sincos((double)gamma[j], &gs, &gc);
        double a2 = Dre * gc - Dim * gs, b2 = Dre * gs + Dim * gc;
        Dre = a2; Dim = b2;
        sincos((double)gamma[j ^ 1], &gs, &gc);
        a2 = Ore * gc - Oim * gs; b2 = Ore * gs + Oim * gc;
        Ore = a2; Oim = b2;
    }
    coef[l * 256 + (j & 7) * 32 + (j >> 3)] =
        make_float4((float)Dre, (float)Dim, (float)Ore, (float)Oim);
}

// Packed complex MZI update (validated rounds 3/4).
__device__ __forceinline__ float2 mzi(float2 cD, float2 cO, float2 y, float2 p) {
    float2 t;
    asm("v_pk_mul_f32 %0, %1, %2 op_sel:[1,1] op_sel_hi:[1,0] neg_lo:[1,0]"
        : "=v"(t) : "v"(cO), "v"(p));
    asm("v_pk_fma_f32 %0, %1, %2, %0 op_sel:[0,0,0] op_sel_hi:[0,1,1]"
        : "+v"(t) : "v"(cO), "v"(p));
    asm("v_pk_fma_f32 %0, %1, %2, %0 op_sel:[1,1,0] op_sel_hi:[1,0,1] neg_lo:[1,0,0]"
        : "+v"(t) : "v"(cD), "v"(y));
    asm("v_pk_fma_f32 %0, %1, %2, %0 op_sel:[0,0,0] op_sel_hi:[0,1,1]"
        : "+v"(t) : "v"(cD), "v"(y));
    return t;
}
__device__ __forceinline__ float2 D_(float4 c) { return make_float2(c.x, c.y); }
__device__ __forceinline__ float2 O_(float4 c) { return make_float2(c.z, c.w); }

// --------------------------------------------------------------------------
// Identity propagation: wave gid propagates basis rows (2 per wave, one per
// lane-half) through layers [mhalf*128, mhalf*128+128).  Mesh math verbatim
// from round 4 (single row-pair slot).  P[row][elem] = result.
// --------------------------------------------------------------------------
__global__ __launch_bounds__(256) void prop_kernel(const float4* __restrict__ coef,
                                                   float2* __restrict__ PA,
                                                   float2* __restrict__ PB) {
    const int lane = threadIdx.x & 63;
    const int wave = threadIdx.x >> 6;
    const int l32  = lane & 31;
    const int half = lane >> 5;
    const int gid  = blockIdx.x * 4 + wave;      // 0..255
    const int mhalf = gid >> 7;                  // 0 = layers 0..127, 1 = 128..255
    const int row  = ((gid & 127) << 1) | half;  // basis row 0..255
    const int l0   = mhalf ? 128 : 0;
    const int idxL4 = (((lane & 32) | ((lane - 1) & 31))) << 2;
    const int idxR4 = (((lane & 32) | ((lane + 1) & 31))) << 2;

    float2 y[8];
#pragma unroll
    for (int j = 0; j < 8; ++j)
        y[j] = make_float2((8 * l32 + j == row) ? 1.f : 0.f, 0.f);

    const float4* cp = coef + l32;
    auto loadl = [&](int l, float4& c0, float4& c1, float4& c2, float4& c3,
                            float4& c4, float4& c5, float4& c6, float4& c7) {
        const float4* p = cp + l * 256;
        c0 = p[0 * 32]; c1 = p[1 * 32]; c2 = p[2 * 32]; c3 = p[3 * 32];
        c4 = p[4 * 32]; c5 = p[5 * 32]; c6 = p[6 * 32]; c7 = p[7 * 32];
    };

    float4 a0, a1, a2, a3, a4, a5, a6, a7;
    float4 b0, b1, b2, b3, b4, b5, b6, b7;
    loadl(l0, a0, a1, a2, a3, a4, a5, a6, a7);

#pragma unroll 1
    for (int it = 0; it < 64; ++it) {
        loadl(l0 + 2 * it + 1, b0, b1, b2, b3, b4, b5, b6, b7);
        {   // even layer
            float2 t0 = y[0], t1 = y[1], t2 = y[2], t3 = y[3];
            float2 t4 = y[4], t5 = y[5], t6 = y[6], t7 = y[7];
            y[0] = mzi(D_(a0), O_(a0), t0, t1);
            y[1] = mzi(D_(a1), O_(a1), t1, t0);
            y[2] = mzi(D_(a2), O_(a2), t2, t3);
            y[3] = mzi(D_(a3), O_(a3), t3, t2);
            y[4] = mzi(D_(a4), O_(a4), t4, t5);
            y[5] = mzi(D_(a5), O_(a5), t5, t4);
            y[6] = mzi(D_(a6), O_(a6), t6, t7);
            y[7] = mzi(D_(a7), O_(a7), t7, t6);
        }
        if (it < 63) loadl(l0 + 2 * it + 2, a0, a1, a2, a3, a4, a5, a6, a7);
        {   // odd layer
            float2 t0 = y[0], t1 = y[1], t2 = y[2], t3 = y[3];
            float2 t4 = y[4], t5 = y[5], t6 = y[6], t7 = y[7];
            float2 plo, phi2;
            plo.x  = __int_as_float(__builtin_amdgcn_ds_bpermute(idxL4, __float_as_int(t7.x)));
            plo.y  = __int_as_float(__builtin_amdgcn_ds_bpermute(idxL4, __float_as_int(t7.y)));
            phi2.x = __int_as_float(__builtin_amdgcn_ds_bpermute(idxR4, __float_as_int(t0.x)));
            phi2.y = __int_as_float(__builtin_amdgcn_ds_bpermute(idxR4, __float_as_int(t0.y)));
            y[1] = mzi(D_(b1), O_(b1), t1, t2);
            y[2] = mzi(D_(b2), O_(b2), t2, t1);
            y[3] = mzi(D_(b3), O_(b3), t3, t4);
            y[4] = mzi(D_(b4), O_(b4), t4, t3);
            y[5] = mzi(D_(b5), O_(b5), t5, t6);
            y[6] = mzi(D_(b6), O_(b6), t6, t5);
            y[0] = mzi(D_(b0), O_(b0), t0, plo);
            y[7] = mzi(D_(b7), O_(b7), t7, phi2);
        }
    }

    float2* P = mhalf ? PB : PA;
#pragma unroll
    for (int j = 0; j < 8; ++j)
        P[row * 256 + 8 * l32 + j] = y[j];
}

// --------------------------------------------------------------------------
// Cm = PA * PB  (complex 256x256, fp32).  block = row i, thread = col j.
// --------------------------------------------------------------------------
__global__ __launch_bounds__(256) void combine_kernel(const float2* __restrict__ PA,
                                                      const float2* __restrict__ PB,
                                                      float2* __restrict__ Cm) {
    int i = blockIdx.x, j = threadIdx.x;
    float accr = 0.f, acci = 0.f;
#pragma unroll 4
    for (int k = 0; k < 256; ++k) {
        float2 a = PA[i * 256 + k];
        float2 b = PB[k * 256 + j];
        accr += a.x * b.x - a.y * b.y;
        acci += a.x * b.y + a.y * b.x;
    }
    Cm[i * 256 + j] = make_float2(accr, acci);
}

// --------------------------------------------------------------------------
// bf16 RNE helpers + 3-way Dekker split.
// --------------------------------------------------------------------------
__device__ __forceinline__ unsigned short bf16rne(float f) {
    unsigned int u = __float_as_uint(f);
    unsigned int r = (u + 0x7FFFu + ((u >> 16) & 1u)) >> 16;
    return (unsigned short)r;
}
__device__ __forceinline__ float bf16f(unsigned short h) {
    return __uint_as_float(((unsigned int)h) << 16);
}
__device__ __forceinline__ void split3(float v, unsigned short& h0,
                                       unsigned short& h1, unsigned short& h2) {
    h0 = bf16rne(v);        float r1 = v - bf16f(h0);
    h1 = bf16rne(r1);       float r2 = r1 - bf16f(h1);
    h2 = bf16rne(r2);
}

// --------------------------------------------------------------------------
// Wt[p][n][k] = bf16 plane p of W[k][n], where W is the real 512x512
// expansion of Cm:  out_real[m][n] = sum_k X[m][k] * W[k][n],
// X = [x_re | x_im], out cols = [re | im].
// --------------------------------------------------------------------------
__global__ __launch_bounds__(256) void wsplit_kernel(const float2* __restrict__ Cm,
                                                     unsigned short* __restrict__ Wt) {
    int idx = blockIdx.x * 256 + threadIdx.x;   // 0..262143
    int n = idx >> 9, k = idx & 511;
    float w;
    if (k < 256) {
        float2 c = Cm[k * 256 + (n & 255)];
        w = (n < 256) ? c.x : c.y;
    } else {
        float2 c = Cm[(k - 256) * 256 + (n & 255)];
        w = (n < 256) ? -c.y : c.x;
    }
    unsigned short h0, h1, h2;
    split3(w, h0, h1, h2);
    Wt[0 * 262144 + n * 512 + k] = h0;
    Wt[1 * 262144 + n * 512 + k] = h1;
    Wt[2 * 262144 + n * 512 + k] = h2;
}

// --------------------------------------------------------------------------
// Main GEMM: out[16384][512] = X[16384][512] * W  (bf16x3, 6 terms i+j<=2).
// 128x128 tile, 4 waves (2x2 of 64x64), BK=32.  a-frag: X[m][k] 8-contig-k;
// b-frag: Wt[n][k] 8-contig-k; D: col=lane&15, row=(lane>>4)*4+e (verified
// gfx950 layouts).  X staged fp32->bf16x3 on the fly.
// --------------------------------------------------------------------------
__global__ __launch_bounds__(256, 2) void gemm_kernel(
        const float* __restrict__ x_re, const float* __restrict__ x_im,
        const unsigned short* __restrict__ Wt, float* __restrict__ out) {
    __shared__ unsigned short XL[3][128][40];
    __shared__ unsigned short WL[3][128][40];

    const int t    = threadIdx.x;
    const int lane = t & 63;
    const int wave = t >> 6;
    const int wm   = wave >> 1, wn = wave & 1;
    const int nt = blockIdx.x & 3, mt = blockIdx.x >> 2;
    const int m0 = mt * 128, n0 = nt * 128;
    const int lr = lane & 15, lg = lane >> 4;   // frag row/col and k-group

    f32x4 acc[4][4];
#pragma unroll
    for (int a = 0; a < 4; ++a)
#pragma unroll
        for (int b = 0; b < 4; ++b) acc[a][b] = (f32x4)0.f;

#pragma unroll 1
    for (int ks = 0; ks < 16; ++ks) {
        const int k0 = ks * 32;
        // ---- stage X tile (128 rows x 32 k), fp32 -> 3 bf16 planes
        const float* xsrc = (k0 < 256) ? x_re : x_im;
        const int kcol = k0 & 255;
#pragma unroll
        for (int r = 0; r < 4; ++r) {
            int F = r * 256 + t;                 // float4 id: row*8 + g
            int row = F >> 3, g = F & 7;
            float4 v = ((const float4*)xsrc)[(m0 + row) * 64 + (kcol >> 2) + g];
            unsigned short h0[4], h1[4], h2[4];
            split3(v.x, h0[0], h1[0], h2[0]);
            split3(v.y, h0[1], h1[1], h2[1]);
            split3(v.z, h0[2], h1[2], h2[2]);
            split3(v.w, h0[3], h1[3], h2[3]);
            *(ushort4*)&XL[0][row][g * 4] = make_ushort4(h0[0], h0[1], h0[2], h0[3]);
            *(ushort4*)&XL[1][row][g * 4] = make_ushort4(h1[0], h1[1], h1[2], h1[3]);
            *(ushort4*)&XL[2][row][g * 4] = make_ushort4(h2[0], h2[1], h2[2], h2[3]);
        }
        // ---- stage W tile (3 planes x 128 n x 32 k), pre-split bf16
#pragma unroll
        for (int r = 0; r < 6; ++r) {
            int U = r * 256 + t;                 // 16B unit id
            int p = U >> 9, rem = U & 511;
            int n = rem >> 2, ku = (rem & 3) * 8;
            uint4 v = ((const uint4*)Wt)[p * 32768 + (n0 + n) * 64 + ((k0 + ku) >> 3)];
            *(uint4*)&WL[p][n][ku] = v;
        }
        __syncthreads();

        // ---- compute: 6 terms (i,j), i+j<=2
        short8 bfr[3][4];
#pragma unroll
        for (int p = 0; p < 3; ++p)
#pragma unroll
            for (int ni = 0; ni < 4; ++ni)
                bfr[p][ni] = *(const short8*)&WL[p][wn * 64 + ni * 16 + lr][lg * 8];

#pragma unroll
        for (int i = 0; i < 3; ++i) {
            short8 af[4];
#pragma unroll
            for (int mi = 0; mi < 4; ++mi)
                af[mi] = *(const short8*)&XL[i][wm * 64 + mi * 16 + lr][lg * 8];
#pragma unroll
            for (int j = 0; j < 3; ++j) {
                if (i + j > 2) continue;
#pragma unroll
                for (int mi = 0; mi < 4; ++mi)
#pragma unroll
                    for (int ni = 0; ni < 4; ++ni)
                        acc[mi][ni] = __builtin_amdgcn_mfma_f32_16x16x32_bf16(
                            af[mi], bfr[j][ni], acc[mi][ni], 0, 0, 0);
            }
        }
        __syncthreads();
    }

    // ---- epilogue
#pragma unroll
    for (int mi = 0; mi < 4; ++mi) {
#pragma unroll
        for (int ni = 0; ni < 4; ++ni) {
            int nglob = n0 + wn * 64 + ni * 16 + lr;
            float* dst = (nglob < 256)
                       ? out + (size_t)(nglob)
                       : out + (size_t)BB * 256 + (nglob - 256);
#pragma unroll
            for (int e = 0; e < 4; ++e) {
                int m = m0 + wm * 64 + mi * 16 + lg * 4 + e;
                dst[(size_t)m * 256] = acc[mi][ni][e];
            }
        }
    }
}

extern "C" void kernel_launch(void* const* d_in, const int* in_sizes, int n_in,
                              void* d_out, int out_size, void* d_ws, size_t ws_size,
                              hipStream_t stream) {
    const float* x_re  = (const float*)d_in[0];
    const float* x_im  = (const float*)d_in[1];
    const float* theta = (const float*)d_in[2];
    const float* phi   = (const float*)d_in[3];
    const float* gamma = (const float*)d_in[4];

    char* ws = (char*)d_ws;
    float4* coef        = (float4*)ws;                                  // 1 MB
    float2* PA          = (float2*)(ws + (1 << 20));                    // 512 KB
    float2* PB          = (float2*)(ws + (1 << 20) + (512 << 10));      // 512 KB
    float2* Cm          = (float2*)(ws + (2 << 20));                    // 512 KB
    unsigned short* Wt  = (unsigned short*)(ws + (2 << 20) + (512 << 10)); // 1.5 MB

    hipLaunchKernelGGL(coef_kernel, dim3(256), dim3(256), 0, stream,
                       theta, phi, gamma, coef);
    hipLaunchKernelGGL(prop_kernel, dim3(64), dim3(256), 0, stream, coef, PA, PB);
    hipLaunchKernelGGL(combine_kernel, dim3(256), dim3(256), 0, stream, PA, PB, Cm);
    hipLaunchKernelGGL(wsplit_kernel, dim3(1024), dim3(256), 0, stream, Cm, Wt);
    hipLaunchKernelGGL(gemm_kernel, dim3(512), dim3(256), 0, stream,
                       x_re, x_im, Wt, (float*)d_out);
}